// Round 1
// baseline (120.648 us; speedup 1.0000x reference)
//
#include <hip/hip_runtime.h>
#include <math.h>

#define Bn 512
#define Wn 512
#define En 512
#define WSPLIT 4
#define WCH (Wn / WSPLIT)   // 128
#define EPSF 1e-5f

// ---- workspace layout (float offsets) ----
#define O_W1T    0                           // En*Wn      = 262144
#define O_SUMW1  (O_W1T + En * Wn)           // + En
#define O_PART   (O_SUMW1 + En)              // + WSPLIT*Bn*En = 1048576
#define O_LIN    (O_PART + WSPLIT * Bn * En) // + Bn*En
#define O_PSUM   (O_LIN + Bn * En)           // + 8*En
#define O_PSUMSQ (O_PSUM + 8 * En)           // + 8*En
#define O_SCALE  (O_PSUMSQ + 8 * En)         // + En
#define O_SHIFT  (O_SCALE + En)              // + En
// total ~1.58M floats ~= 6.1 MB

// W1 [E,W] -> W1T [W,E], LDS-tiled transpose
__global__ void k_transpose(const float* __restrict__ w1, float* __restrict__ w1t) {
    __shared__ float tile[32][33];
    int bx = blockIdx.x, by = blockIdx.y;     // bx: w-tile, by: e-tile
    int tx = threadIdx.x, ty = threadIdx.y;   // (32, 8)
#pragma unroll
    for (int j = 0; j < 32; j += 8)
        tile[ty + j][tx] = w1[(size_t)(by * 32 + ty + j) * Wn + bx * 32 + tx];
    __syncthreads();
#pragma unroll
    for (int j = 0; j < 32; j += 8)
        w1t[(size_t)(bx * 32 + ty + j) * En + by * 32 + tx] = tile[tx][ty + j];
}

// sumW1[e] = sum_w W1[e,w]; one wave per row
__global__ void k_sumw1(const float* __restrict__ w1, float* __restrict__ sumw1) {
    int e = blockIdx.x;
    int l = threadIdx.x;  // 64
    const float* row = w1 + (size_t)e * Wn;
    float s = 0.f;
#pragma unroll
    for (int j = 0; j < Wn; j += 64) s += row[j + l];
#pragma unroll
    for (int off = 32; off; off >>= 1) s += __shfl_down(s, off);
    if (l == 0) sumw1[e] = s;
}

// partial[wc][b][e] = sum_{w in chunk wc} x[b,w,e] * W1T[w,e]
__global__ __launch_bounds__(128) void k_lin_partial(const float* __restrict__ x,
                                                     const float* __restrict__ w1t,
                                                     float* __restrict__ part) {
    int b = blockIdx.x, wc = blockIdx.y;
    int e4 = threadIdx.x;  // float4 index over e
    const float4* xp = (const float4*)x + ((size_t)b * Wn + (size_t)wc * WCH) * (En / 4) + e4;
    const float4* wp = (const float4*)w1t + (size_t)(wc * WCH) * (En / 4) + e4;
    float ax = 0.f, ay = 0.f, az = 0.f, aw = 0.f;
#pragma unroll 4
    for (int w = 0; w < WCH; ++w) {
        float4 xv = xp[(size_t)w * (En / 4)];
        float4 wv = wp[(size_t)w * (En / 4)];
        ax += xv.x * wv.x;
        ay += xv.y * wv.y;
        az += xv.z * wv.z;
        aw += xv.w * wv.w;
    }
    float4 r;
    r.x = ax; r.y = ay; r.z = az; r.w = aw;
    ((float4*)part)[((size_t)wc * Bn + b) * (En / 4) + e4] = r;
}

// lin[b][e] = sum_wc part - x_last[b][e]*sumW1[e] + b1[e]
__global__ __launch_bounds__(128) void k_lin_reduce(const float* __restrict__ part,
                                                    const float* __restrict__ x,
                                                    const float* __restrict__ sumw1,
                                                    const float* __restrict__ b1,
                                                    float* __restrict__ lin) {
    int b = blockIdx.x;
    int e4 = threadIdx.x;
    const float4* p = (const float4*)part;
    float sx = 0.f, sy = 0.f, sz = 0.f, sw = 0.f;
#pragma unroll
    for (int wc = 0; wc < WSPLIT; ++wc) {
        float4 v = p[((size_t)wc * Bn + b) * (En / 4) + e4];
        sx += v.x; sy += v.y; sz += v.z; sw += v.w;
    }
    float4 xl = ((const float4*)x)[((size_t)b * Wn + (Wn - 1)) * (En / 4) + e4];
    float4 s1 = ((const float4*)sumw1)[e4];
    float4 bb = ((const float4*)b1)[e4];
    float4 r;
    r.x = sx - xl.x * s1.x + bb.x;
    r.y = sy - xl.y * s1.y + bb.y;
    r.z = sz - xl.z * s1.z + bb.z;
    r.w = sw - xl.w * s1.w + bb.w;
    ((float4*)lin)[(size_t)b * (En / 4) + e4] = r;
}

// per-e partial sums over 64 b's per block (coalesced over e)
__global__ void k_stats_partial(const float* __restrict__ lin,
                                float* __restrict__ psum, float* __restrict__ psumsq) {
    int blk = blockIdx.x;  // 8
    int e = threadIdx.x;   // 512
    float s = 0.f, q = 0.f;
    int b0 = blk * 64;
    for (int b = b0; b < b0 + 64; ++b) {
        float v = lin[(size_t)b * En + e];
        s += v;
        q += v * v;
    }
    psum[blk * En + e] = s;
    psumsq[blk * En + e] = q;
}

__global__ void k_stats_final(const float* __restrict__ psum, const float* __restrict__ psumsq,
                              const float* __restrict__ gamma, const float* __restrict__ beta,
                              float* __restrict__ scale, float* __restrict__ shift) {
    int e = threadIdx.x;  // 512
    float s = 0.f, q = 0.f;
#pragma unroll
    for (int c = 0; c < 8; ++c) {
        s += psum[c * En + e];
        q += psumsq[c * En + e];
    }
    float mean = s * (1.f / Bn);
    float var = q * (1.f / Bn) - mean * mean;
    float sc = gamma[e] * rsqrtf(var + EPSF);
    scale[e] = sc;
    shift[e] = beta[e] - mean * sc;
}

// out[b] = sum_e (lin*scale + shift + seq_last) * W2[e]  + b2
__global__ __launch_bounds__(128) void k_out(const float* __restrict__ lin,
                                             const float* __restrict__ x,
                                             const float* __restrict__ scale,
                                             const float* __restrict__ shift,
                                             const float* __restrict__ w2,
                                             const float* __restrict__ b2,
                                             float* __restrict__ out) {
    int b = blockIdx.x;
    int t = threadIdx.x;  // 128 -> float4 over e
    float4 l  = ((const float4*)lin)[(size_t)b * (En / 4) + t];
    float4 xl = ((const float4*)x)[((size_t)b * Wn + (Wn - 1)) * (En / 4) + t];
    float4 sc = ((const float4*)scale)[t];
    float4 sh = ((const float4*)shift)[t];
    float4 wv = ((const float4*)w2)[t];
    float v = (l.x * sc.x + sh.x + xl.x) * wv.x
            + (l.y * sc.y + sh.y + xl.y) * wv.y
            + (l.z * sc.z + sh.z + xl.z) * wv.z
            + (l.w * sc.w + sh.w + xl.w) * wv.w;
#pragma unroll
    for (int off = 32; off; off >>= 1) v += __shfl_down(v, off);
    __shared__ float red[2];
    int wid = t >> 6, lane = t & 63;
    if (lane == 0) red[wid] = v;
    __syncthreads();
    if (t == 0) out[b] = red[0] + red[1] + b2[0];
}

extern "C" void kernel_launch(void* const* d_in, const int* in_sizes, int n_in,
                              void* d_out, int out_size, void* d_ws, size_t ws_size,
                              hipStream_t stream) {
    const float* x     = (const float*)d_in[0];
    const float* w1    = (const float*)d_in[1];
    const float* b1    = (const float*)d_in[2];
    const float* gamma = (const float*)d_in[3];
    const float* beta  = (const float*)d_in[4];
    const float* w2    = (const float*)d_in[5];
    const float* b2    = (const float*)d_in[6];
    float* out = (float*)d_out;
    float* ws  = (float*)d_ws;

    float* w1t    = ws + O_W1T;
    float* sumw1  = ws + O_SUMW1;
    float* part   = ws + O_PART;
    float* lin    = ws + O_LIN;
    float* psum   = ws + O_PSUM;
    float* psumsq = ws + O_PSUMSQ;
    float* scale  = ws + O_SCALE;
    float* shift  = ws + O_SHIFT;

    k_transpose<<<dim3(Wn / 32, En / 32), dim3(32, 8), 0, stream>>>(w1, w1t);
    k_sumw1<<<En, 64, 0, stream>>>(w1, sumw1);
    k_lin_partial<<<dim3(Bn, WSPLIT), 128, 0, stream>>>(x, w1t, part);
    k_lin_reduce<<<Bn, 128, 0, stream>>>(part, x, sumw1, b1, lin);
    k_stats_partial<<<8, 512, 0, stream>>>(lin, psum, psumsq);
    k_stats_final<<<1, 512, 0, stream>>>(psum, psumsq, gamma, beta, scale, shift);
    k_out<<<Bn, 128, 0, stream>>>(lin, x, scale, shift, w2, b2, out);
}

// Round 3
// 108.121 us; speedup vs baseline: 1.1159x; 1.1159x over previous
//
#include <hip/hip_runtime.h>
#include <math.h>

#define Bn 512
#define Wn 512
#define En 512
#define EPSF 1e-5f

typedef float fx4 __attribute__((ext_vector_type(4)));

// ---- workspace layout (float offsets) ----
#define O_W1T    0                           // En*Wn = 262144
#define O_LIN    (O_W1T + En * Wn)           // + Bn*En
#define O_PSUM   (O_LIN + Bn * En)           // + 8*En
#define O_PSUMSQ (O_PSUM + 8 * En)           // + 8*En

// W1 [E,W] -> W1T [W,E], LDS-tiled transpose
__global__ void k_transpose(const float* __restrict__ w1, float* __restrict__ w1t) {
    __shared__ float tile[32][33];
    int bx = blockIdx.x, by = blockIdx.y;     // bx: w-tile, by: e-tile
    int tx = threadIdx.x, ty = threadIdx.y;   // (32, 8)
#pragma unroll
    for (int j = 0; j < 32; j += 8)
        tile[ty + j][tx] = w1[(size_t)(by * 32 + ty + j) * Wn + bx * 32 + tx];
    __syncthreads();
#pragma unroll
    for (int j = 0; j < 32; j += 8)
        w1t[(size_t)(bx * 32 + ty + j) * En + by * 32 + tx] = tile[tx][ty + j];
}

// One block per b. 512 threads = 4 w-subchunks x 128 e4-lanes.
// Computes lin[b][e] = sum_w x*W1T - x_last*sumW1 + b1 in one pass,
// with sumW1 accumulated for free alongside the dot product.
__global__ __launch_bounds__(512) void k_main(const float* __restrict__ x,
                                              const float* __restrict__ w1t,
                                              const float* __restrict__ b1,
                                              float* __restrict__ lin) {
    int b = blockIdx.x;
    int tid = threadIdx.x;
    int wsub = tid >> 7;      // 0..3
    int e4 = tid & 127;       // float4 index over e

    const fx4* xp = (const fx4*)x + ((size_t)b * Wn + (size_t)wsub * 128) * (En / 4) + e4;
    const fx4* wp = (const fx4*)w1t + (size_t)(wsub * 128) * (En / 4) + e4;

    fx4 acc = {0.f, 0.f, 0.f, 0.f};
    fx4 wsum = {0.f, 0.f, 0.f, 0.f};
#pragma unroll 8
    for (int w = 0; w < 128; ++w) {
        fx4 xv = __builtin_nontemporal_load(&xp[(size_t)w * (En / 4)]);
        fx4 wv = wp[(size_t)w * (En / 4)];
        acc += xv * wv;
        wsum += wv;
    }

    __shared__ fx4 lacc[4][128];
    __shared__ fx4 lws[4][128];
    lacc[wsub][e4] = acc;
    lws[wsub][e4] = wsum;
    __syncthreads();

    if (wsub == 0) {
        fx4 t = lacc[0][e4], u = lws[0][e4];
#pragma unroll
        for (int k = 1; k < 4; ++k) {
            t += lacc[k][e4];
            u += lws[k][e4];
        }
        fx4 xl = ((const fx4*)x)[((size_t)b * Wn + (Wn - 1)) * (En / 4) + e4];
        fx4 bb = ((const fx4*)b1)[e4];
        fx4 r = t - xl * u + bb;
        ((fx4*)lin)[(size_t)b * (En / 4) + e4] = r;
    }
}

// per-e partial sums over 64 b's per block (coalesced over e)
__global__ void k_stats_partial(const float* __restrict__ lin,
                                float* __restrict__ psum, float* __restrict__ psumsq) {
    int blk = blockIdx.x;  // 8
    int e = threadIdx.x;   // 512
    float s = 0.f, q = 0.f;
    int b0 = blk * 64;
#pragma unroll 4
    for (int b = b0; b < b0 + 64; ++b) {
        float v = lin[(size_t)b * En + e];
        s += v;
        q += v * v;
    }
    psum[blk * En + e] = s;
    psumsq[blk * En + e] = q;
}

// out[b] = sum_e (lin*scale + shift + seq_last) * W2[e] + b2
// stats_final (8-way psum reduce -> scale/shift) inlined per block (L2-hit).
__global__ __launch_bounds__(128) void k_out(const float* __restrict__ lin,
                                             const float* __restrict__ x,
                                             const float* __restrict__ psum,
                                             const float* __restrict__ psumsq,
                                             const float* __restrict__ gamma,
                                             const float* __restrict__ beta,
                                             const float* __restrict__ w2,
                                             const float* __restrict__ b2,
                                             float* __restrict__ out) {
    int b = blockIdx.x;
    int t = threadIdx.x;  // 128 -> float4 over e

    fx4 s4 = {0.f, 0.f, 0.f, 0.f}, q4 = {0.f, 0.f, 0.f, 0.f};
#pragma unroll
    for (int c = 0; c < 8; ++c) {
        s4 += ((const fx4*)psum)[c * (En / 4) + t];
        q4 += ((const fx4*)psumsq)[c * (En / 4) + t];
    }
    fx4 g = ((const fx4*)gamma)[t];
    fx4 be = ((const fx4*)beta)[t];
    fx4 mean = s4 * (1.f / Bn);
    fx4 var = q4 * (1.f / Bn) - mean * mean;
    fx4 sc, sh;
    sc.x = g.x * rsqrtf(var.x + EPSF); sc.y = g.y * rsqrtf(var.y + EPSF);
    sc.z = g.z * rsqrtf(var.z + EPSF); sc.w = g.w * rsqrtf(var.w + EPSF);
    sh = be - mean * sc;

    fx4 l  = ((const fx4*)lin)[(size_t)b * (En / 4) + t];
    fx4 xl = ((const fx4*)x)[((size_t)b * Wn + (Wn - 1)) * (En / 4) + t];
    fx4 wv = ((const fx4*)w2)[t];
    fx4 term = (l * sc + sh + xl) * wv;
    float v = term.x + term.y + term.z + term.w;
#pragma unroll
    for (int off = 32; off; off >>= 1) v += __shfl_down(v, off);
    __shared__ float red[2];
    int wid = t >> 6, lane = t & 63;
    if (lane == 0) red[wid] = v;
    __syncthreads();
    if (t == 0) out[b] = red[0] + red[1] + b2[0];
}

extern "C" void kernel_launch(void* const* d_in, const int* in_sizes, int n_in,
                              void* d_out, int out_size, void* d_ws, size_t ws_size,
                              hipStream_t stream) {
    const float* x     = (const float*)d_in[0];
    const float* w1    = (const float*)d_in[1];
    const float* b1    = (const float*)d_in[2];
    const float* gamma = (const float*)d_in[3];
    const float* beta  = (const float*)d_in[4];
    const float* w2    = (const float*)d_in[5];
    const float* b2    = (const float*)d_in[6];
    float* out = (float*)d_out;
    float* ws  = (float*)d_ws;

    float* w1t    = ws + O_W1T;
    float* lin    = ws + O_LIN;
    float* psum   = ws + O_PSUM;
    float* psumsq = ws + O_PSUMSQ;

    k_transpose<<<dim3(Wn / 32, En / 32), dim3(32, 8), 0, stream>>>(w1, w1t);
    k_main<<<Bn, 512, 0, stream>>>(x, w1t, b1, lin);
    k_stats_partial<<<8, 512, 0, stream>>>(lin, psum, psumsq);
    k_out<<<Bn, 128, 0, stream>>>(lin, x, psum, psumsq, gamma, beta, w2, b2, out);
}